// Round 1
// baseline (229.989 us; speedup 1.0000x reference)
//
#include <hip/hip_runtime.h>

#define BB 8
#define LL 8192
#define TT 32
#define SM 5
#define LOUT (LL - SM + 1)        // 8188
#define NTOT (BB * LOUT)          // 65504
#define NBINS 1000
#define CHUNK 1024                // samples per block (per track)

__device__ __forceinline__ int bin_of(float v) {
    // clip(v, 0, 10-1e-8) then searchsorted(edges[1:-1], v, 'left')
    v = fminf(fmaxf(v, 0.0f), 10.0f);
    int b = (int)ceilf(v * 100.0f) - 1;
    b = b < 0 ? 0 : b;
    return b > (NBINS - 1) ? (NBINS - 1) : b;
}

__global__ __launch_bounds__(256) void ghm_hist_kernel(
    const float* __restrict__ yp, const float* __restrict__ yt,
    int* __restrict__ pred_hist, int* __restrict__ targ_hist,
    int* __restrict__ joint_hist)
{
    __shared__ int s_pred[NBINS];
    __shared__ int s_targ[NBINS];

    const int t   = blockIdx.y;          // track, wave-uniform
    const int tid = threadIdx.x;
    const int lane = tid & 63;

    for (int i = tid; i < NBINS; i += 256) { s_pred[i] = 0; s_targ[i] = 0; }
    __syncthreads();

    int* __restrict__ joint_t = joint_hist + (size_t)t * (NBINS * NBINS);

    const int n0 = blockIdx.x * CHUNK;

    #pragma unroll
    for (int it = 0; it < CHUNK / 256; ++it) {
        const int n = n0 + it * 256 + tid;
        bool have = (n < NTOT);
        int pb = 0, tb = 0;
        if (have) {
            const int b = n / LOUT;
            const int l = n - b * LOUT;
            const size_t base = ((size_t)(b * LL + l)) * TT + t;
            float ps = 0.f, ts = 0.f;
            #pragma unroll
            for (int k = 0; k < SM; ++k) {
                ps += yp[base + (size_t)k * TT];
                ts += yt[base + (size_t)k * TT];
            }
            ps *= 0.2f; ts *= 0.2f;
            if (isfinite(ps) && isfinite(ts)) {
                pb = bin_of(ps);
                tb = bin_of(ts);
            } else {
                have = false;
            }
        }

        // Dedup the hot (0,0) joint bin within each wave: one atomic per wave.
        const bool hot = have && (pb == 0) && (tb == 0);
        const unsigned long long hotmask = __ballot(hot);
        if (hot) {
            const unsigned long long lower =
                hotmask & ((lane == 0) ? 0ull : (~0ull >> (64 - lane)));
            if (lower == 0ull) {  // leader
                atomicAdd(&joint_t[0], (int)__popcll(hotmask));
            }
        } else if (have) {
            atomicAdd(&joint_t[pb * NBINS + tb], 1);
        }

        if (have) {
            atomicAdd(&s_pred[pb], 1);
            atomicAdd(&s_targ[tb], 1);
        }
    }

    __syncthreads();
    for (int i = tid; i < NBINS; i += 256) {
        int c = s_pred[i];
        if (c) atomicAdd(&pred_hist[t * NBINS + i], c);
        c = s_targ[i];
        if (c) atomicAdd(&targ_hist[t * NBINS + i], c);
    }
}

extern "C" void kernel_launch(void* const* d_in, const int* in_sizes, int n_in,
                              void* d_out, int out_size, void* d_ws, size_t ws_size,
                              hipStream_t stream) {
    const float* yp = (const float*)d_in[0];
    const float* yt = (const float*)d_in[1];
    int* out = (int*)d_out;

    // Zero all outputs (atomic-accumulated below); stream-ordered, capture-safe.
    hipMemsetAsync(d_out, 0, (size_t)out_size * sizeof(int), stream);

    int* pred  = out;
    int* targ  = out + TT * NBINS;
    int* joint = out + 2 * TT * NBINS;

    dim3 grid((NTOT + CHUNK - 1) / CHUNK, TT);  // (64, 32)
    ghm_hist_kernel<<<grid, 256, 0, stream>>>(yp, yt, pred, targ, joint);
}

// Round 2
// 76.632 us; speedup vs baseline: 3.0012x; 3.0012x over previous
//
#include <hip/hip_runtime.h>

#define LL 8192
#define TT 32
#define NB 8
#define NG_PER_B 2047                 // 4-sample groups per batch (2047*4 = 8188 samples)
#define NGROUPS (NB * NG_PER_B)       // 16376
#define NBINS 1000

// ---- per-track LDS region layout (ints) ----
//  [0,256)    : joint block  pb<16 && tb<16   (idx = pb*16 + tb)
//  [256,496)  : joint row strip pb==0, tb in [16,256)
//  [496,736)  : joint col strip tb==0, pb in [16,256)
//  [736,872)  : pred marginal bins [0,136)
//  [872,1008) : targ marginal bins [0,136)
#define REG_SZ 1008
#define REG_STRIDE 1009               // 1009 % 32 = 17 (odd) -> track bases spread over banks
#define TPB 16                        // tracks per block
#define THREADS 512
#define SLOTS 32                      // THREADS / TPB group-slots per pass
#define GROUPS_PER_BLOCK 128          // 4 passes of 32 slots
#define MARG_COV 136

__device__ __forceinline__ int bin_of(float v) {
    v = fminf(fmaxf(v, 0.0f), 10.0f);
    int b = (int)ceilf(v * 100.0f) - 1;
    b = b < 0 ? 0 : b;
    return b > (NBINS - 1) ? (NBINS - 1) : b;
}

__global__ __launch_bounds__(256) void zero_kernel(int4* __restrict__ p, int n4) {
    int i = blockIdx.x * 256 + threadIdx.x;
    if (i < n4) p[i] = make_int4(0, 0, 0, 0);
}

__global__ __launch_bounds__(THREADS) void ghm_hist(
    const float* __restrict__ yp, const float* __restrict__ yt,
    int* __restrict__ out)
{
    __shared__ int s_h[TPB * REG_STRIDE];   // 64,576 B

    const int tid  = threadIdx.x;
    const int trk  = tid & (TPB - 1);
    const int slot = tid >> 4;              // 0..31
    const int t    = blockIdx.y * TPB + trk;

    for (int i = tid; i < TPB * REG_STRIDE; i += THREADS) s_h[i] = 0;
    __syncthreads();

    int* __restrict__ reg = &s_h[trk * REG_STRIDE];

    int* __restrict__ pred_g  = out;
    int* __restrict__ targ_g  = out + TT * NBINS;
    int* __restrict__ joint_g = out + 2 * TT * NBINS;
    int* __restrict__ joint_t = joint_g + (size_t)t * NBINS * NBINS;

    int c00 = 0, cp0 = 0, ct0 = 0;

    const int g0 = blockIdx.x * GROUPS_PER_BLOCK;
    #pragma unroll
    for (int pass = 0; pass < GROUPS_PER_BLOCK / SLOTS; ++pass) {
        const int g = g0 + pass * SLOTS + slot;
        if (g < NGROUPS) {
            const int b = g / NG_PER_B;
            const int j = g - b * NG_PER_B;     // 4-sample group within batch
            const size_t base = ((size_t)b * LL + 4 * (size_t)j) * TT + t;
            float xp[8], xt[8];
            #pragma unroll
            for (int k = 0; k < 8; ++k) {
                xp[k] = yp[base + (size_t)k * TT];   // coalesced across lanes (trk fastest)
                xt[k] = yt[base + (size_t)k * TT];
            }
            #pragma unroll
            for (int r = 0; r < 4; ++r) {
                const float ps = (xp[r] + xp[r+1] + xp[r+2] + xp[r+3] + xp[r+4]) * 0.2f;
                const float ts = (xt[r] + xt[r+1] + xt[r+2] + xt[r+3] + xt[r+4]) * 0.2f;
                if (!(isfinite(ps) && isfinite(ts))) continue;
                const int pb = bin_of(ps);
                const int tb = bin_of(ts);

                // marginals (hot bin 0 in registers)
                if (pb == 0)             cp0++;
                else if (pb < MARG_COV)  atomicAdd(&reg[736 + pb], 1);
                else                     atomicAdd(&pred_g[t * NBINS + pb], 1);

                if (tb == 0)             ct0++;
                else if (tb < MARG_COV)  atomicAdd(&reg[872 + tb], 1);
                else                     atomicAdd(&targ_g[t * NBINS + tb], 1);

                // joint
                if (pb == 0 && tb == 0)        c00++;
                else if (pb < 16 && tb < 16)   atomicAdd(&reg[pb * 16 + tb], 1);
                else if (pb == 0 && tb < 256)  atomicAdd(&reg[256 + tb - 16], 1);
                else if (tb == 0 && pb < 256)  atomicAdd(&reg[496 + pb - 16], 1);
                else                           atomicAdd(&joint_t[pb * NBINS + tb], 1);
            }
        }
    }

    // fold register counters into LDS
    if (c00) atomicAdd(&reg[0],   c00);
    if (cp0) atomicAdd(&reg[736], cp0);
    if (ct0) atomicAdd(&reg[872], ct0);
    __syncthreads();

    // flush LDS region to global
    const int h0 = blockIdx.y * TPB;
    for (int i = tid; i < TPB * REG_SZ; i += THREADS) {
        const int tr = i / REG_SZ;
        const int sl = i - tr * REG_SZ;
        const int c  = s_h[tr * REG_STRIDE + sl];
        if (c == 0) continue;
        const int tg = h0 + tr;
        if (sl < 256) {
            const int pb = sl >> 4, tb = sl & 15;
            atomicAdd(&joint_g[(size_t)tg * NBINS * NBINS + pb * NBINS + tb], c);
        } else if (sl < 496) {
            const int tb = sl - 256 + 16;
            atomicAdd(&joint_g[(size_t)tg * NBINS * NBINS + tb], c);
        } else if (sl < 736) {
            const int pb = sl - 496 + 16;
            atomicAdd(&joint_g[(size_t)tg * NBINS * NBINS + pb * NBINS], c);
        } else if (sl < 872) {
            atomicAdd(&pred_g[tg * NBINS + (sl - 736)], c);
        } else {
            atomicAdd(&targ_g[tg * NBINS + (sl - 872)], c);
        }
    }
}

extern "C" void kernel_launch(void* const* d_in, const int* in_sizes, int n_in,
                              void* d_out, int out_size, void* d_ws, size_t ws_size,
                              hipStream_t stream) {
    const float* yp = (const float*)d_in[0];
    const float* yt = (const float*)d_in[1];
    int* out = (int*)d_out;

    const int n4 = out_size / 4;                      // out_size = 32,064,000 (÷4 exact)
    zero_kernel<<<(n4 + 255) / 256, 256, 0, stream>>>((int4*)out, n4);

    dim3 grid((NGROUPS + GROUPS_PER_BLOCK - 1) / GROUPS_PER_BLOCK, TT / TPB);  // (128, 2)
    ghm_hist<<<grid, THREADS, 0, stream>>>(yp, yt, out);
}